// Round 4
// baseline (380.909 us; speedup 1.0000x reference)
//
#include <hip/hip_runtime.h>
#include <math.h>

#define T_SEQ 2048
#define NB 2
#define NH 16
#define DH 64
#define DM 1024

typedef unsigned short u16;
typedef __attribute__((ext_vector_type(8))) __bf16 bf16x8;
typedef __attribute__((ext_vector_type(4))) float f32x4;
typedef __attribute__((ext_vector_type(4))) int i32x4;

__device__ __forceinline__ u16 f2bf(float f) {
  unsigned u = __builtin_bit_cast(unsigned, f);
  u += 0x7FFFu + ((u >> 16) & 1u);   // RNE
  return (u16)(u >> 16);
}
__device__ __forceinline__ float bf2f(u16 v) {
  unsigned u = ((unsigned)v) << 16;
  return __builtin_bit_cast(float, u);
}
// Aliasing-safe vector moves (memcpy carries no TBAA tag; emits b128/dwordx4)
__device__ __forceinline__ bf16x8 ld_frag(const u16* p) {
  bf16x8 r; __builtin_memcpy(&r, p, 16); return r;
}
__device__ __forceinline__ i32x4 ld16(const u16* p) {
  i32x4 r; __builtin_memcpy(&r, p, 16); return r;
}
__device__ __forceinline__ void st16(u16* p, i32x4 v) {
  __builtin_memcpy(p, &v, 16);
}
// Load 8 f32 from global, convert RNE -> 8 bf16, store 16B to LDS.
__device__ __forceinline__ void cvt_store8(u16* dst, const float* src) {
  f32x4 a, b;
  __builtin_memcpy(&a, src, 16);
  __builtin_memcpy(&b, src + 4, 16);
  u16 t[8];
  t[0] = f2bf(a[0]); t[1] = f2bf(a[1]); t[2] = f2bf(a[2]); t[3] = f2bf(a[3]);
  t[4] = f2bf(b[0]); t[5] = f2bf(b[1]); t[6] = f2bf(b[2]); t[7] = f2bf(b[3]);
  __builtin_memcpy(dst, t, 16);
}

// ---------------------------------------------------------------------------
// NT GEMM: C[M][N] = A[M][K] @ B[N][K]^T + bias[N], fp32 acc, bf16 MFMA.
// MODE 0: A,B f32 global; scatter epilogue -> q/k/v ws [B][H][T][DH] bf16.
// MODE 1: A bf16 ws, B f32 global; epilogue -> f32 row-major out (exact add).
// Tile 128x128, BK=32, 4 waves 2x2, each wave 64x64 = 4x4 MFMA 16x16x32.
// ---------------------------------------------------------------------------
template <int MODE>
__global__ __launch_bounds__(256) void gemm_nt(
    const void* __restrict__ A, const float* __restrict__ Bw,
    const float* __restrict__ bias, float* __restrict__ out,
    u16* __restrict__ q_ws, u16* __restrict__ k_ws, u16* __restrict__ v_ws,
    int M, int N, int K) {
  __shared__ __align__(16) u16 As[128 * 32];
  __shared__ __align__(16) u16 Bs[128 * 32];
  const int tid = threadIdx.x;
  const int wave = tid >> 6, lane = tid & 63;
  const int quad = lane >> 4, l16 = lane & 15;
  const int wm = wave & 1, wn = wave >> 1;
  const int m0 = blockIdx.y * 128, n0 = blockIdx.x * 128;
  const int srow = tid >> 2;            // 0..63
  const int schunk = (tid & 3) * 8;     // element offset of 16B(bf16) chunk

  f32x4 acc[4][4] = {};

  const float* Af = (const float*)A + (long)(m0 + srow) * K + schunk;
  const u16*   Ab = (const u16*)A + (long)(m0 + srow) * K + schunk;
  const float* Bg = Bw + (long)(n0 + srow) * K + schunk;

  for (int k0 = 0; k0 < K; k0 += 32) {
    __syncthreads();
    if constexpr (MODE == 0) {
      cvt_store8(&As[srow * 32 + schunk],        Af + k0);
      cvt_store8(&As[(srow + 64) * 32 + schunk], Af + (long)64 * K + k0);
    } else {
      st16(&As[srow * 32 + schunk],        ld16(Ab + k0));
      st16(&As[(srow + 64) * 32 + schunk], ld16(Ab + (long)64 * K + k0));
    }
    cvt_store8(&Bs[srow * 32 + schunk],        Bg + k0);
    cvt_store8(&Bs[(srow + 64) * 32 + schunk], Bg + (long)64 * K + k0);
    __syncthreads();
    bf16x8 af[4], bfr[4];
#pragma unroll
    for (int mt = 0; mt < 4; mt++)
      af[mt] = ld_frag(&As[(wm * 64 + mt * 16 + l16) * 32 + quad * 8]);
#pragma unroll
    for (int nt = 0; nt < 4; nt++)
      bfr[nt] = ld_frag(&Bs[(wn * 64 + nt * 16 + l16) * 32 + quad * 8]);
#pragma unroll
    for (int mt = 0; mt < 4; mt++)
#pragma unroll
      for (int nt = 0; nt < 4; nt++)
        acc[mt][nt] = __builtin_amdgcn_mfma_f32_16x16x32_bf16(af[mt], bfr[nt],
                                                              acc[mt][nt], 0, 0, 0);
  }

#pragma unroll
  for (int nt = 0; nt < 4; nt++) {
    const int col = n0 + wn * 64 + nt * 16 + l16;
    const float bv = bias[col];
    if constexpr (MODE == 1) {
#pragma unroll
      for (int mt = 0; mt < 4; mt++) {
        const int rbase = m0 + wm * 64 + mt * 16 + quad * 4;
#pragma unroll
        for (int r = 0; r < 4; r++)
          out[(long)(rbase + r) * N + col] = acc[mt][nt][r] + bv;
      }
    } else {
      const int which = col >> 10;
      const int rem = col & 1023;
      const int h = rem >> 6, dh = rem & 63;
      u16* dst = (which == 0) ? q_ws : (which == 1) ? k_ws : v_ws;
#pragma unroll
      for (int mt = 0; mt < 4; mt++) {
        const int rbase = m0 + wm * 64 + mt * 16 + quad * 4;
#pragma unroll
        for (int r = 0; r < 4; r++) {
          const int m = rbase + r;
          const int b = m >> 11, t = m & (T_SEQ - 1);
          dst[(((long)(b * NH + h)) * T_SEQ + t) * DH + dh] = f2bf(acc[mt][nt][r] + bv);
        }
      }
    }
  }
}

// ---------------------------------------------------------------------------
// RoPE in place on q,k ws (bf16) [B*H][T][64]. Folds 1/sqrt(64) into q
// (exact: power of two). Angles in f32 (matches the f32 np reference).
// ---------------------------------------------------------------------------
__global__ __launch_bounds__(256) void rope_kernel(u16* __restrict__ q,
                                                   u16* __restrict__ k) {
  const int idx = blockIdx.x * 256 + threadIdx.x;  // B*H*T*32 threads
  const int i = idx & 31;
  const int t = (idx >> 5) & (T_SEQ - 1);
  const int bh = idx >> 16;
  const long base = ((long)bh * T_SEQ + t) * DH;
  // inv_freq = 10000^(-i/32) = 2^(-i * log2(10000)/32)
  const float invf = exp2f(-(float)i * 0.41524101186092045f);
  const float ang = (float)t * invf;
  const float c = cosf(ang), s = sinf(ang);
  const float q1 = bf2f(q[base + i]), q2 = bf2f(q[base + i + 32]);
  const float k1 = bf2f(k[base + i]), k2 = bf2f(k[base + i + 32]);
  q[base + i]      = f2bf((q1 * c - q2 * s) * 0.125f);
  q[base + i + 32] = f2bf((q2 * c + q1 * s) * 0.125f);
  k[base + i]      = f2bf(k1 * c - k2 * s);
  k[base + i + 32] = f2bf(k2 * c + k1 * s);
}

// ---------------------------------------------------------------------------
// Flash attention (causal). Block = (qblk, bh): 64 q rows, 256 threads.
// Wave w owns q rows [q0+16w, q0+16w+16) -> no cross-wave softmax state.
// K tile [64 keys][64] and V^T [64 feat][64 keys] staged in LDS per tile.
// S via 2 MFMA k-steps; P -> per-wave LDS (C-layout -> A-layout); PV MFMA.
// ---------------------------------------------------------------------------
__global__ __launch_bounds__(256) void attn_kernel(const u16* __restrict__ q,
                                                   const u16* __restrict__ k,
                                                   const u16* __restrict__ v,
                                                   u16* __restrict__ o) {
  __shared__ __align__(16) u16 Ks[64 * 64];
  __shared__ __align__(16) u16 Vt[64 * 64];
  __shared__ __align__(16) u16 Pbuf[4][16 * 64];
  const int tid = threadIdx.x;
  const int wave = tid >> 6, lane = tid & 63;
  const int quad = lane >> 4, l16 = lane & 15;
  const int qblk = blockIdx.x;   // 0..31
  const int bh = blockIdx.y;     // 0..31
  const int q0 = qblk * 64;
  const long base = (long)bh * T_SEQ * DH;

  // Q fragments for this wave's 16 rows (score scale folded in by rope)
  bf16x8 aq0, aq1;
  {
    const u16* qr = q + base + (long)(q0 + wave * 16 + l16) * DH + quad * 8;
    aq0 = ld_frag(qr);
    aq1 = ld_frag(qr + 32);
  }

  float mst[4], lst[4];
  f32x4 oacc[4] = {};
#pragma unroll
  for (int r = 0; r < 4; r++) { mst[r] = -1e30f; lst[r] = 0.f; }

  const int row_g = q0 + wave * 16 + quad * 4;  // + r
  const int ntiles = qblk + 1;

  for (int kt = 0; kt < ntiles; kt++) {
    __syncthreads();
    {  // stage K and V^T
      const int rr = tid >> 3;            // 0..31
      const int cc = (tid & 7) * 8;       // chunk start
      const u16* kp = k + base + (long)kt * 64 * DH;
      const u16* vp = v + base + (long)kt * 64 * DH;
      st16(&Ks[rr * 64 + cc],        ld16(&kp[rr * 64 + cc]));
      st16(&Ks[(rr + 32) * 64 + cc], ld16(&kp[(rr + 32) * 64 + cc]));
      union { i32x4 v4; u16 e[8]; } u0, u1;
      u0.v4 = ld16(&vp[rr * 64 + cc]);
      u1.v4 = ld16(&vp[(rr + 32) * 64 + cc]);
#pragma unroll
      for (int j = 0; j < 8; j++) {
        Vt[(cc + j) * 64 + rr]      = u0.e[j];
        Vt[(cc + j) * 64 + rr + 32] = u1.e[j];
      }
    }
    __syncthreads();

    // S = Q K^T  (16 x 64 per wave)
    f32x4 sfr[4];
#pragma unroll
    for (int nt = 0; nt < 4; nt++) {
      bf16x8 b0 = ld_frag(&Ks[(nt * 16 + l16) * 64 + quad * 8]);
      bf16x8 b1 = ld_frag(&Ks[(nt * 16 + l16) * 64 + 32 + quad * 8]);
      f32x4 z = {0.f, 0.f, 0.f, 0.f};
      z = __builtin_amdgcn_mfma_f32_16x16x32_bf16(aq0, b0, z, 0, 0, 0);
      z = __builtin_amdgcn_mfma_f32_16x16x32_bf16(aq1, b1, z, 0, 0, 0);
      sfr[nt] = z;
    }

    // causal mask + row max
    float rmax[4];
#pragma unroll
    for (int r = 0; r < 4; r++) rmax[r] = -1e30f;
#pragma unroll
    for (int nt = 0; nt < 4; nt++) {
      const int colg = kt * 64 + nt * 16 + l16;
#pragma unroll
      for (int r = 0; r < 4; r++) {
        float sv = sfr[nt][r];
        sv = (colg <= row_g + r) ? sv : -1e30f;
        sfr[nt][r] = sv;
        rmax[r] = fmaxf(rmax[r], sv);
      }
    }
#pragma unroll
    for (int off = 1; off < 16; off <<= 1)
#pragma unroll
      for (int r = 0; r < 4; r++)
        rmax[r] = fmaxf(rmax[r], __shfl_xor(rmax[r], off, 64));

    float alpha[4], rsum[4];
#pragma unroll
    for (int r = 0; r < 4; r++) {
      const float mnew = fmaxf(mst[r], rmax[r]);
      alpha[r] = exp2f((mst[r] - mnew) * 1.44269504f);
      mst[r] = mnew;
      rsum[r] = 0.f;
    }
    // P = exp(S - m) -> per-wave LDS [16][64] row-major
#pragma unroll
    for (int nt = 0; nt < 4; nt++) {
#pragma unroll
      for (int r = 0; r < 4; r++) {
        const float p = exp2f((sfr[nt][r] - mst[r]) * 1.44269504f);
        rsum[r] += p;
        Pbuf[wave][(quad * 4 + r) * 64 + nt * 16 + l16] = f2bf(p);
      }
    }
#pragma unroll
    for (int off = 1; off < 16; off <<= 1)
#pragma unroll
      for (int r = 0; r < 4; r++) rsum[r] += __shfl_xor(rsum[r], off, 64);
#pragma unroll
    for (int r = 0; r < 4; r++) lst[r] = lst[r] * alpha[r] + rsum[r];
#pragma unroll
    for (int ont = 0; ont < 4; ont++)
#pragma unroll
      for (int r = 0; r < 4; r++) oacc[ont][r] *= alpha[r];

    // Make P-stores visible before the A-layout re-read.
    __syncthreads();

    bf16x8 ap0 = ld_frag(&Pbuf[wave][l16 * 64 + quad * 8]);
    bf16x8 ap1 = ld_frag(&Pbuf[wave][l16 * 64 + 32 + quad * 8]);
#pragma unroll
    for (int ont = 0; ont < 4; ont++) {
      bf16x8 bv0 = ld_frag(&Vt[(ont * 16 + l16) * 64 + quad * 8]);
      bf16x8 bv1 = ld_frag(&Vt[(ont * 16 + l16) * 64 + 32 + quad * 8]);
      oacc[ont] = __builtin_amdgcn_mfma_f32_16x16x32_bf16(ap0, bv0, oacc[ont], 0, 0, 0);
      oacc[ont] = __builtin_amdgcn_mfma_f32_16x16x32_bf16(ap1, bv1, oacc[ont], 0, 0, 0);
    }
  }

  // epilogue: O / l -> attn_out ws [B][T][C] bf16
  const int b = bh >> 4, h = bh & 15;
#pragma unroll
  for (int ont = 0; ont < 4; ont++) {
#pragma unroll
    for (int r = 0; r < 4; r++) {
      const float val = oacc[ont][r] / lst[r];
      const int row = row_g + r;
      o[((long)(b * T_SEQ + row)) * DM + h * DH + ont * 16 + l16] = f2bf(val);
    }
  }
}

// ---------------------------------------------------------------------------
extern "C" void kernel_launch(void* const* d_in, const int* in_sizes, int n_in,
                              void* d_out, int out_size, void* d_ws, size_t ws_size,
                              hipStream_t stream) {
  const float* x      = (const float*)d_in[0];
  const float* qkv_w  = (const float*)d_in[1];
  const float* qkv_b  = (const float*)d_in[2];
  const float* proj_w = (const float*)d_in[3];
  const float* proj_b = (const float*)d_in[4];
  float* out = (float*)d_out;

  u16* ws = (u16*)d_ws;
  const long per = (long)NB * NH * T_SEQ * DH;  // 4,194,304 elems = 8 MB bf16
  u16* q_ws = ws;
  u16* k_ws = ws + per;
  u16* v_ws = ws + 2 * per;
  u16* ao_ws = ws + 3 * per;  // [B][T][C] bf16, 8 MB

  dim3 blk(256);
  gemm_nt<0><<<dim3(24, 32), blk, 0, stream>>>(x, qkv_w, qkv_b, nullptr,
                                               q_ws, k_ws, v_ws, 4096, 3072, 1024);
  rope_kernel<<<8192, 256, 0, stream>>>(q_ws, k_ws);
  attn_kernel<<<dim3(32, 32), blk, 0, stream>>>(q_ws, k_ws, v_ws, ao_ws);
  gemm_nt<1><<<dim3(8, 32), blk, 0, stream>>>(ao_ws, proj_w, proj_b, out,
                                              nullptr, nullptr, nullptr, 4096, 1024, 1024);
}

// Round 5
// 269.094 us; speedup vs baseline: 1.4155x; 1.4155x over previous
//
#include <hip/hip_runtime.h>
#include <math.h>

#define T_SEQ 2048
#define NB 2
#define NH 16
#define DH 64
#define DM 1024

typedef unsigned short u16;
typedef __attribute__((ext_vector_type(8))) __bf16 bf16x8;
typedef __attribute__((ext_vector_type(4))) float f32x4;
typedef __attribute__((ext_vector_type(4))) int i32x4;

__device__ __forceinline__ u16 f2bf(float f) {
  unsigned u = __builtin_bit_cast(unsigned, f);
  u += 0x7FFFu + ((u >> 16) & 1u);   // RNE
  return (u16)(u >> 16);
}
__device__ __forceinline__ float bf2f(u16 v) {
  unsigned u = ((unsigned)v) << 16;
  return __builtin_bit_cast(float, u);
}
// Aliasing-safe vector moves (memcpy: no TBAA tag; emits b128/dwordx4)
__device__ __forceinline__ bf16x8 ld_frag(const u16* p) {
  bf16x8 r; __builtin_memcpy(&r, p, 16); return r;
}
__device__ __forceinline__ i32x4 ld16(const u16* p) {
  i32x4 r; __builtin_memcpy(&r, p, 16); return r;
}
__device__ __forceinline__ void st16(u16* p, i32x4 v) {
  __builtin_memcpy(p, &v, 16);
}
// Load 8 f32, convert RNE -> 8 bf16, store 16B.
__device__ __forceinline__ void cvt_store8(u16* dst, const float* src) {
  f32x4 a, b;
  __builtin_memcpy(&a, src, 16);
  __builtin_memcpy(&b, src + 4, 16);
  u16 t[8];
  t[0] = f2bf(a[0]); t[1] = f2bf(a[1]); t[2] = f2bf(a[2]); t[3] = f2bf(a[3]);
  t[4] = f2bf(b[0]); t[5] = f2bf(b[1]); t[6] = f2bf(b[2]); t[7] = f2bf(b[3]);
  __builtin_memcpy(dst, t, 16);
}

// f32 -> bf16 elementwise (8 elems/thread)
__global__ __launch_bounds__(256) void cvt_f32_bf16(const float* __restrict__ in,
                                                    u16* __restrict__ out, int n8) {
  const int i = blockIdx.x * 256 + threadIdx.x;
  if (i < n8) cvt_store8(out + (long)i * 8, in + (long)i * 8);
}

// ---------------------------------------------------------------------------
// NT GEMM: C[M][N] = A[M][K] @ B[N][K]^T + bias[N]; A bf16, B f32 (cvt on
// stage), fp32 acc. LDS rows padded 32->40 u16 (80B, 16B-aligned, ~2-way
// banks instead of the 2-start-bank pattern of stride 64B).
// MODE 0: scatter -> q,k natural [B][H][T][DH]; V TRANSPOSED [B][H][DH][T]
//         (kills the per-tile LDS transpose in attention).
// MODE 1: f32 row-major out.
// ---------------------------------------------------------------------------
template <int MODE>
__global__ __launch_bounds__(256) void gemm_nt(
    const u16* __restrict__ A, const float* __restrict__ Bw,
    const float* __restrict__ bias, float* __restrict__ out,
    u16* __restrict__ q_ws, u16* __restrict__ k_ws, u16* __restrict__ v_ws,
    int M, int N, int K) {
  __shared__ __align__(16) u16 As[128 * 40];
  __shared__ __align__(16) u16 Bs[128 * 40];
  const int tid = threadIdx.x;
  const int wave = tid >> 6, lane = tid & 63;
  const int quad = lane >> 4, l16 = lane & 15;
  const int wm = wave & 1, wn = wave >> 1;
  const int m0 = blockIdx.y * 128, n0 = blockIdx.x * 128;
  const int srow = tid >> 2;            // 0..63
  const int schunk = (tid & 3) * 8;     // 8-element chunk offset

  f32x4 acc[4][4] = {};

  const u16*   Ab = A + (long)(m0 + srow) * K + schunk;
  const float* Bg = Bw + (long)(n0 + srow) * K + schunk;

  for (int k0 = 0; k0 < K; k0 += 32) {
    __syncthreads();
    st16(&As[srow * 40 + schunk],        ld16(Ab + k0));
    st16(&As[(srow + 64) * 40 + schunk], ld16(Ab + (long)64 * K + k0));
    cvt_store8(&Bs[srow * 40 + schunk],        Bg + k0);
    cvt_store8(&Bs[(srow + 64) * 40 + schunk], Bg + (long)64 * K + k0);
    __syncthreads();
    bf16x8 af[4], bfr[4];
#pragma unroll
    for (int mt = 0; mt < 4; mt++)
      af[mt] = ld_frag(&As[(wm * 64 + mt * 16 + l16) * 40 + quad * 8]);
#pragma unroll
    for (int nt = 0; nt < 4; nt++)
      bfr[nt] = ld_frag(&Bs[(wn * 64 + nt * 16 + l16) * 40 + quad * 8]);
#pragma unroll
    for (int mt = 0; mt < 4; mt++)
#pragma unroll
      for (int nt = 0; nt < 4; nt++)
        acc[mt][nt] = __builtin_amdgcn_mfma_f32_16x16x32_bf16(af[mt], bfr[nt],
                                                              acc[mt][nt], 0, 0, 0);
  }

#pragma unroll
  for (int nt = 0; nt < 4; nt++) {
    const int col = n0 + wn * 64 + nt * 16 + l16;
    const float bv = bias[col];
    if constexpr (MODE == 1) {
#pragma unroll
      for (int mt = 0; mt < 4; mt++) {
        const int rbase = m0 + wm * 64 + mt * 16 + quad * 4;
#pragma unroll
        for (int r = 0; r < 4; r++)
          out[(long)(rbase + r) * N + col] = acc[mt][nt][r] + bv;
      }
    } else {
      const int which = col >> 10;      // 0=q 1=k 2=v (uniform per nt)
      const int rem = col & 1023;
      const int h = rem >> 6, dh = rem & 63;
#pragma unroll
      for (int mt = 0; mt < 4; mt++) {
        const int rbase = m0 + wm * 64 + mt * 16 + quad * 4;
#pragma unroll
        for (int r = 0; r < 4; r++) {
          const int m = rbase + r;
          const int b = m >> 11, t = m & (T_SEQ - 1);
          const u16 val = f2bf(acc[mt][nt][r] + bv);
          if (which == 0)
            q_ws[(((long)(b * NH + h)) * T_SEQ + t) * DH + dh] = val;
          else if (which == 1)
            k_ws[(((long)(b * NH + h)) * T_SEQ + t) * DH + dh] = val;
          else  // V stored transposed: [B][H][DH][T]
            v_ws[(((long)(b * NH + h)) * DH + dh) * T_SEQ + t] = val;
        }
      }
    }
  }
}

// ---------------------------------------------------------------------------
// RoPE in place on q,k (bf16, natural layout). Folds 1/sqrt(64) into q.
// ---------------------------------------------------------------------------
__global__ __launch_bounds__(256) void rope_kernel(u16* __restrict__ q,
                                                   u16* __restrict__ k) {
  const int idx = blockIdx.x * 256 + threadIdx.x;  // B*H*T*32 threads
  const int i = idx & 31;
  const int t = (idx >> 5) & (T_SEQ - 1);
  const int bh = idx >> 16;
  const long base = ((long)bh * T_SEQ + t) * DH;
  const float invf = exp2f(-(float)i * 0.41524101186092045f);  // 10000^(-i/32)
  const float ang = (float)t * invf;
  const float c = cosf(ang), s = sinf(ang);
  const float q1 = bf2f(q[base + i]), q2 = bf2f(q[base + i + 32]);
  const float k1 = bf2f(k[base + i]), k2 = bf2f(k[base + i + 32]);
  q[base + i]      = f2bf((q1 * c - q2 * s) * 0.125f);
  q[base + i + 32] = f2bf((q2 * c + q1 * s) * 0.125f);
  k[base + i]      = f2bf(k1 * c - k2 * s);
  k[base + i + 32] = f2bf(k2 * c + k1 * s);
}

// ---------------------------------------------------------------------------
// Flash attention (causal), rebuilt:
//  - block (jp, bh) processes q-tiles {jp, 31-jp}: 17 key-tiles each -> flat
//    load balance (was 1..32 -> tail-bound, 14% occupancy).
//  - 128-key K-tiles: 2 barriers / 128 keys (was 6).
//  - V^T comes pre-transposed from gemm0 -> vector-staged, no scalar LDS
//    transpose (was the 3.19e7 bank conflicts).
//  - LDS rows padded: Ks 72, Vt/Pbuf 136 u16 (16B-aligned, spread banks).
//  - P C->A layout round-trip stays wave-local: ds_writes then
//    s_waitcnt lgkmcnt(0) (DS ops are in-order per wave), no 3rd barrier.
// LDS: 18432 + 17408 + 17408 = 53248 B -> 3 blocks/CU.
// ---------------------------------------------------------------------------
__global__ __launch_bounds__(256) void attn_kernel(const u16* __restrict__ q,
                                                   const u16* __restrict__ k,
                                                   const u16* __restrict__ v,
                                                   u16* __restrict__ o) {
  __shared__ __align__(16) u16 Ks[128 * 72];
  __shared__ __align__(16) u16 Vt[64 * 136];
  __shared__ __align__(16) u16 Pbuf[4][16 * 136];
  const int tid = threadIdx.x;
  const int wave = tid >> 6, lane = tid & 63;
  const int quad = lane >> 4, l16 = lane & 15;
  const int jp = blockIdx.x;     // 0..15 -> q-tiles {jp, 31-jp}
  const int bh = blockIdx.y;     // 0..31
  const long base = (long)bh * T_SEQ * DH;   // same elem count for q,k,v
  const int b = bh >> 4, h = bh & 15;

  for (int half = 0; half < 2; half++) {
    const int qt = half ? (31 - jp) : jp;
    const int q0 = qt * 64;
    // Q fragments for this wave's 16 rows (scale folded in by rope)
    bf16x8 aq0, aq1;
    {
      const u16* qr = q + base + (long)(q0 + wave * 16 + l16) * DH + quad * 8;
      aq0 = ld_frag(qr);
      aq1 = ld_frag(qr + 32);
    }
    float mst[4], lst[4];
    f32x4 oacc[4] = {};
#pragma unroll
    for (int r = 0; r < 4; r++) { mst[r] = -1e30f; lst[r] = 0.f; }
    const int row_g = q0 + wave * 16 + quad * 4;  // + r
    const int nkt = (q0 + 64 + 127) >> 7;         // 128-key tiles

    for (int kt = 0; kt < nkt; kt++) {
      const int key0 = kt * 128;
      __syncthreads();
      {  // stage K [128][72] and V^T [64][136] — all vector, coalesced
        const u16* kp = k + base + (long)key0 * DH;
#pragma unroll
        for (int p = 0; p < 4; p++) {
          const int rr = (tid >> 3) + p * 32;
          const int cc = (tid & 7) * 8;
          st16(&Ks[rr * 72 + cc], ld16(kp + rr * 64 + cc));
        }
        const u16* vp = v + base + key0;
#pragma unroll
        for (int p = 0; p < 4; p++) {
          const int d = (tid >> 4) + p * 16;
          const int cc = (tid & 15) * 8;
          st16(&Vt[d * 136 + cc], ld16(vp + (long)d * T_SEQ + cc));
        }
      }
      __syncthreads();

      // S = Q K^T  (16 x 128 per wave)
      f32x4 sfr[8];
#pragma unroll
      for (int nt = 0; nt < 8; nt++) {
        bf16x8 b0 = ld_frag(&Ks[(nt * 16 + l16) * 72 + quad * 8]);
        bf16x8 b1 = ld_frag(&Ks[(nt * 16 + l16) * 72 + 32 + quad * 8]);
        f32x4 z = {0.f, 0.f, 0.f, 0.f};
        z = __builtin_amdgcn_mfma_f32_16x16x32_bf16(aq0, b0, z, 0, 0, 0);
        z = __builtin_amdgcn_mfma_f32_16x16x32_bf16(aq1, b1, z, 0, 0, 0);
        sfr[nt] = z;
      }

      // causal mask only on the diagonal tile (uniform branch)
      if (kt == nkt - 1) {
#pragma unroll
        for (int nt = 0; nt < 8; nt++) {
          const int colg = key0 + nt * 16 + l16;
#pragma unroll
          for (int r = 0; r < 4; r++)
            sfr[nt][r] = (colg <= row_g + r) ? sfr[nt][r] : -1e30f;
        }
      }

      // row max over 128 keys: 8 regs local + 4 shfls
      float rmax[4];
#pragma unroll
      for (int r = 0; r < 4; r++) {
        float m = sfr[0][r];
#pragma unroll
        for (int nt = 1; nt < 8; nt++) m = fmaxf(m, sfr[nt][r]);
        rmax[r] = m;
      }
#pragma unroll
      for (int off = 1; off < 16; off <<= 1)
#pragma unroll
        for (int r = 0; r < 4; r++)
          rmax[r] = fmaxf(rmax[r], __shfl_xor(rmax[r], off, 64));

      float alpha[4], rsum[4];
#pragma unroll
      for (int r = 0; r < 4; r++) {
        const float mnew = fmaxf(mst[r], rmax[r]);
        alpha[r] = exp2f((mst[r] - mnew) * 1.44269504f);
        mst[r] = mnew;
        rsum[r] = 0.f;
      }
      // P = exp(S-m) -> per-wave LDS [16][136] (A-layout source)
#pragma unroll
      for (int nt = 0; nt < 8; nt++) {
#pragma unroll
        for (int r = 0; r < 4; r++) {
          const float p = exp2f((sfr[nt][r] - mst[r]) * 1.44269504f);
          rsum[r] += p;
          Pbuf[wave][(quad * 4 + r) * 136 + nt * 16 + l16] = f2bf(p);
        }
      }
#pragma unroll
      for (int off = 1; off < 16; off <<= 1)
#pragma unroll
        for (int r = 0; r < 4; r++) rsum[r] += __shfl_xor(rsum[r], off, 64);
#pragma unroll
      for (int r = 0; r < 4; r++) lst[r] = lst[r] * alpha[r] + rsum[r];
#pragma unroll
      for (int ont = 0; ont < 4; ont++)
#pragma unroll
        for (int r = 0; r < 4; r++) oacc[ont][r] *= alpha[r];

      // wave-local RAW on Pbuf: DS ops complete in order per wave
      asm volatile("s_waitcnt lgkmcnt(0)" ::: "memory");

      bf16x8 ap[4];
#pragma unroll
      for (int c = 0; c < 4; c++)
        ap[c] = ld_frag(&Pbuf[wave][l16 * 136 + c * 32 + quad * 8]);
#pragma unroll
      for (int ont = 0; ont < 4; ont++) {
#pragma unroll
        for (int c = 0; c < 4; c++) {
          bf16x8 bv = ld_frag(&Vt[(ont * 16 + l16) * 136 + c * 32 + quad * 8]);
          oacc[ont] = __builtin_amdgcn_mfma_f32_16x16x32_bf16(ap[c], bv, oacc[ont], 0, 0, 0);
        }
      }
    }

    // epilogue: O / l -> attn_out ws [B][T][C] bf16
#pragma unroll
    for (int ont = 0; ont < 4; ont++) {
#pragma unroll
      for (int r = 0; r < 4; r++) {
        const float val = oacc[ont][r] / lst[r];
        const int row = row_g + r;
        o[((long)(b * T_SEQ + row)) * DM + h * DH + ont * 16 + l16] = f2bf(val);
      }
    }
  }
}

// ---------------------------------------------------------------------------
extern "C" void kernel_launch(void* const* d_in, const int* in_sizes, int n_in,
                              void* d_out, int out_size, void* d_ws, size_t ws_size,
                              hipStream_t stream) {
  const float* x      = (const float*)d_in[0];
  const float* qkv_w  = (const float*)d_in[1];
  const float* qkv_b  = (const float*)d_in[2];
  const float* proj_w = (const float*)d_in[3];
  const float* proj_b = (const float*)d_in[4];
  float* out = (float*)d_out;

  u16* ws = (u16*)d_ws;
  const long per = (long)NB * NH * T_SEQ * DH;  // 4,194,304 elems = 8.39 MB bf16
  u16* q_ws = ws;
  u16* k_ws = ws + per;
  u16* v_ws = ws + 2 * per;              // transposed [B][H][DH][T]
  u16* ao_ws = ws + 3 * per;             // aliases x_bf (x dead after gemm0)
  u16* x_bf  = ws + 3 * per;

  dim3 blk(256);
  // x f32 -> bf16 (4M elems / 8 per thread)
  cvt_f32_bf16<<<2048, blk, 0, stream>>>(x, x_bf, (int)(per / 8));
  gemm_nt<0><<<dim3(24, 32), blk, 0, stream>>>(x_bf, qkv_w, qkv_b, nullptr,
                                               q_ws, k_ws, v_ws, 4096, 3072, 1024);
  rope_kernel<<<8192, blk, 0, stream>>>(q_ws, k_ws);
  attn_kernel<<<dim3(16, 32), blk, 0, stream>>>(q_ws, k_ws, v_ws, ao_ws);
  gemm_nt<1><<<dim3(8, 32), blk, 0, stream>>>(ao_ws, proj_w, proj_b, out,
                                              nullptr, nullptr, nullptr, 4096, 1024, 1024);
}

// Round 6
// 230.090 us; speedup vs baseline: 1.6555x; 1.1695x over previous
//
#include <hip/hip_runtime.h>
#include <math.h>

#define T_SEQ 2048
#define NB 2
#define NH 16
#define DH 64
#define DM 1024

typedef unsigned short u16;
typedef __attribute__((ext_vector_type(8))) __bf16 bf16x8;
typedef __attribute__((ext_vector_type(4))) float f32x4;
typedef __attribute__((ext_vector_type(4))) int i32x4;

__device__ __forceinline__ u16 f2bf(float f) {
  unsigned u = __builtin_bit_cast(unsigned, f);
  u += 0x7FFFu + ((u >> 16) & 1u);   // RNE
  return (u16)(u >> 16);
}
__device__ __forceinline__ float bf2f(u16 v) {
  unsigned u = ((unsigned)v) << 16;
  return __builtin_bit_cast(float, u);
}
// Aliasing-safe vector moves (memcpy: no TBAA tag; emits b128/dwordx4)
__device__ __forceinline__ bf16x8 ld_frag(const u16* p) {
  bf16x8 r; __builtin_memcpy(&r, p, 16); return r;
}
__device__ __forceinline__ i32x4 ld16(const u16* p) {
  i32x4 r; __builtin_memcpy(&r, p, 16); return r;
}
__device__ __forceinline__ void st16(u16* p, i32x4 v) {
  __builtin_memcpy(p, &v, 16);
}
// Load 8 f32, convert RNE -> 8 bf16, store 16B.
__device__ __forceinline__ void cvt_store8(u16* dst, const float* src) {
  f32x4 a, b;
  __builtin_memcpy(&a, src, 16);
  __builtin_memcpy(&b, src + 4, 16);
  u16 t[8];
  t[0] = f2bf(a[0]); t[1] = f2bf(a[1]); t[2] = f2bf(a[2]); t[3] = f2bf(a[3]);
  t[4] = f2bf(b[0]); t[5] = f2bf(b[1]); t[6] = f2bf(b[2]); t[7] = f2bf(b[3]);
  __builtin_memcpy(dst, t, 16);
}
// Async 16B global -> LDS (direct DMA, no VGPR round trip).
__device__ __forceinline__ void gld_lds16(const u16* g, u16* l) {
  __builtin_amdgcn_global_load_lds(
      (const __attribute__((address_space(1))) void*)g,
      (__attribute__((address_space(3))) void*)l, 16, 0, 0);
}

// f32 -> bf16 elementwise (8 elems/thread)
__global__ __launch_bounds__(256) void cvt_f32_bf16(const float* __restrict__ in,
                                                    u16* __restrict__ out, int n8) {
  const int i = blockIdx.x * 256 + threadIdx.x;
  if (i < n8) cvt_store8(out + (long)i * 8, in + (long)i * 8);
}

// ---------------------------------------------------------------------------
// NT GEMM, m97-style: C[M][N] = A[M][K] @ B[N][K]^T + bias[N]; A,B bf16 in
// global, fp32 acc. Staging via global_load_lds width=16 (4 insts/thread per
// BK=32 step), LDS UNPADDED (lane-ordered destination requirement:
// lane -> row=lane/4, chunk=(lane&3)*8 gives dst = base + lane*16 exactly).
// Tile 128x128, 4 waves 2x2, each wave 64x64 = 4x4 MFMA 16x16x32.
// MODE 0: scatter -> q,k natural [B][H][T][DH]; V TRANSPOSED [B][H][DH][T].
// MODE 1: f32 row-major out.
// ---------------------------------------------------------------------------
template <int MODE>
__global__ __launch_bounds__(256) void gemm_nt(
    const u16* __restrict__ A, const u16* __restrict__ Bw,
    const float* __restrict__ bias, float* __restrict__ out,
    u16* __restrict__ q_ws, u16* __restrict__ k_ws, u16* __restrict__ v_ws,
    int M, int N, int K) {
  __shared__ __align__(16) u16 As[128 * 32];
  __shared__ __align__(16) u16 Bs[128 * 32];
  const int tid = threadIdx.x;
  const int wave = tid >> 6, lane = tid & 63;
  const int quad = lane >> 4, l16 = lane & 15;
  const int wm = wave & 1, wn = wave >> 1;
  const int m0 = blockIdx.y * 128, n0 = blockIdx.x * 128;
  const int lrow = lane >> 2;           // 0..15 (row within wave's 16-row slab)
  const int lcol = (lane & 3) * 8;      // 8-elem chunk offset

  f32x4 acc[4][4] = {};

  // lane's global source rows; wave w covers rows w*16..w*16+15 (+64 for p=1)
  const u16* Ag = A + (long)(m0 + wave * 16 + lrow) * K + lcol;
  const u16* Bg = Bw + (long)(n0 + wave * 16 + lrow) * K + lcol;
  // matching LDS destinations (elem offsets; byte = base + lane*16)
  u16* Al = &As[(wave * 16 + lrow) * 32 + lcol];
  u16* Bl = &Bs[(wave * 16 + lrow) * 32 + lcol];

  for (int k0 = 0; k0 < K; k0 += 32) {
    __syncthreads();
    gld_lds16(Ag + k0, Al);
    gld_lds16(Ag + (long)64 * K + k0, Al + 64 * 32);
    gld_lds16(Bg + k0, Bl);
    gld_lds16(Bg + (long)64 * K + k0, Bl + 64 * 32);
    __syncthreads();
    bf16x8 af[4], bfr[4];
#pragma unroll
    for (int mt = 0; mt < 4; mt++)
      af[mt] = ld_frag(&As[(wm * 64 + mt * 16 + l16) * 32 + quad * 8]);
#pragma unroll
    for (int nt = 0; nt < 4; nt++)
      bfr[nt] = ld_frag(&Bs[(wn * 64 + nt * 16 + l16) * 32 + quad * 8]);
#pragma unroll
    for (int mt = 0; mt < 4; mt++)
#pragma unroll
      for (int nt = 0; nt < 4; nt++)
        acc[mt][nt] = __builtin_amdgcn_mfma_f32_16x16x32_bf16(af[mt], bfr[nt],
                                                              acc[mt][nt], 0, 0, 0);
  }

#pragma unroll
  for (int nt = 0; nt < 4; nt++) {
    const int col = n0 + wn * 64 + nt * 16 + l16;
    const float bv = bias[col];
    if constexpr (MODE == 1) {
#pragma unroll
      for (int mt = 0; mt < 4; mt++) {
        const int rbase = m0 + wm * 64 + mt * 16 + quad * 4;
#pragma unroll
        for (int r = 0; r < 4; r++)
          out[(long)(rbase + r) * N + col] = acc[mt][nt][r] + bv;
      }
    } else {
      const int which = col >> 10;      // 0=q 1=k 2=v
      const int rem = col & 1023;
      const int h = rem >> 6, dh = rem & 63;
#pragma unroll
      for (int mt = 0; mt < 4; mt++) {
        const int rbase = m0 + wm * 64 + mt * 16 + quad * 4;
#pragma unroll
        for (int r = 0; r < 4; r++) {
          const int m = rbase + r;
          const int b = m >> 11, t = m & (T_SEQ - 1);
          const u16 val = f2bf(acc[mt][nt][r] + bv);
          if (which == 0)
            q_ws[(((long)(b * NH + h)) * T_SEQ + t) * DH + dh] = val;
          else if (which == 1)
            k_ws[(((long)(b * NH + h)) * T_SEQ + t) * DH + dh] = val;
          else  // V stored transposed: [B][H][DH][T]
            v_ws[(((long)(b * NH + h)) * DH + dh) * T_SEQ + t] = val;
        }
      }
    }
  }
}

// ---------------------------------------------------------------------------
// RoPE in place on q,k (bf16, natural layout). Folds 1/sqrt(64) into q.
// ---------------------------------------------------------------------------
__global__ __launch_bounds__(256) void rope_kernel(u16* __restrict__ q,
                                                   u16* __restrict__ k) {
  const int idx = blockIdx.x * 256 + threadIdx.x;  // B*H*T*32 threads
  const int i = idx & 31;
  const int t = (idx >> 5) & (T_SEQ - 1);
  const int bh = idx >> 16;
  const long base = ((long)bh * T_SEQ + t) * DH;
  const float invf = exp2f(-(float)i * 0.41524101186092045f);  // 10000^(-i/32)
  const float ang = (float)t * invf;
  const float c = cosf(ang), s = sinf(ang);
  const float q1 = bf2f(q[base + i]), q2 = bf2f(q[base + i + 32]);
  const float k1 = bf2f(k[base + i]), k2 = bf2f(k[base + i + 32]);
  q[base + i]      = f2bf((q1 * c - q2 * s) * 0.125f);
  q[base + i + 32] = f2bf((q2 * c + q1 * s) * 0.125f);
  k[base + i]      = f2bf(k1 * c - k2 * s);
  k[base + i + 32] = f2bf(k2 * c + k1 * s);
}

// ---------------------------------------------------------------------------
// Flash attention (causal) — unchanged from R5 (225 -> <90 us after the
// transpose/barrier/pairing fixes; will re-profile once gemm is fixed).
// ---------------------------------------------------------------------------
__global__ __launch_bounds__(256) void attn_kernel(const u16* __restrict__ q,
                                                   const u16* __restrict__ k,
                                                   const u16* __restrict__ v,
                                                   u16* __restrict__ o) {
  __shared__ __align__(16) u16 Ks[128 * 72];
  __shared__ __align__(16) u16 Vt[64 * 136];
  __shared__ __align__(16) u16 Pbuf[4][16 * 136];
  const int tid = threadIdx.x;
  const int wave = tid >> 6, lane = tid & 63;
  const int quad = lane >> 4, l16 = lane & 15;
  const int jp = blockIdx.x;     // 0..15 -> q-tiles {jp, 31-jp}
  const int bh = blockIdx.y;     // 0..31
  const long base = (long)bh * T_SEQ * DH;
  const int b = bh >> 4, h = bh & 15;

  for (int half = 0; half < 2; half++) {
    const int qt = half ? (31 - jp) : jp;
    const int q0 = qt * 64;
    bf16x8 aq0, aq1;
    {
      const u16* qr = q + base + (long)(q0 + wave * 16 + l16) * DH + quad * 8;
      aq0 = ld_frag(qr);
      aq1 = ld_frag(qr + 32);
    }
    float mst[4], lst[4];
    f32x4 oacc[4] = {};
#pragma unroll
    for (int r = 0; r < 4; r++) { mst[r] = -1e30f; lst[r] = 0.f; }
    const int row_g = q0 + wave * 16 + quad * 4;  // + r
    const int nkt = (q0 + 64 + 127) >> 7;         // 128-key tiles

    for (int kt = 0; kt < nkt; kt++) {
      const int key0 = kt * 128;
      __syncthreads();
      {  // stage K [128][72] and V^T [64][136] — all vector, coalesced
        const u16* kp = k + base + (long)key0 * DH;
#pragma unroll
        for (int p = 0; p < 4; p++) {
          const int rr = (tid >> 3) + p * 32;
          const int cc = (tid & 7) * 8;
          st16(&Ks[rr * 72 + cc], ld16(kp + rr * 64 + cc));
        }
        const u16* vp = v + base + key0;
#pragma unroll
        for (int p = 0; p < 4; p++) {
          const int d = (tid >> 4) + p * 16;
          const int cc = (tid & 15) * 8;
          st16(&Vt[d * 136 + cc], ld16(vp + (long)d * T_SEQ + cc));
        }
      }
      __syncthreads();

      // S = Q K^T  (16 x 128 per wave)
      f32x4 sfr[8];
#pragma unroll
      for (int nt = 0; nt < 8; nt++) {
        bf16x8 b0 = ld_frag(&Ks[(nt * 16 + l16) * 72 + quad * 8]);
        bf16x8 b1 = ld_frag(&Ks[(nt * 16 + l16) * 72 + 32 + quad * 8]);
        f32x4 z = {0.f, 0.f, 0.f, 0.f};
        z = __builtin_amdgcn_mfma_f32_16x16x32_bf16(aq0, b0, z, 0, 0, 0);
        z = __builtin_amdgcn_mfma_f32_16x16x32_bf16(aq1, b1, z, 0, 0, 0);
        sfr[nt] = z;
      }

      if (kt == nkt - 1) {  // causal mask, diagonal tile only
#pragma unroll
        for (int nt = 0; nt < 8; nt++) {
          const int colg = key0 + nt * 16 + l16;
#pragma unroll
          for (int r = 0; r < 4; r++)
            sfr[nt][r] = (colg <= row_g + r) ? sfr[nt][r] : -1e30f;
        }
      }

      float rmax[4];
#pragma unroll
      for (int r = 0; r < 4; r++) {
        float m = sfr[0][r];
#pragma unroll
        for (int nt = 1; nt < 8; nt++) m = fmaxf(m, sfr[nt][r]);
        rmax[r] = m;
      }
#pragma unroll
      for (int off = 1; off < 16; off <<= 1)
#pragma unroll
        for (int r = 0; r < 4; r++)
          rmax[r] = fmaxf(rmax[r], __shfl_xor(rmax[r], off, 64));

      float alpha[4], rsum[4];
#pragma unroll
      for (int r = 0; r < 4; r++) {
        const float mnew = fmaxf(mst[r], rmax[r]);
        alpha[r] = exp2f((mst[r] - mnew) * 1.44269504f);
        mst[r] = mnew;
        rsum[r] = 0.f;
      }
#pragma unroll
      for (int nt = 0; nt < 8; nt++) {
#pragma unroll
        for (int r = 0; r < 4; r++) {
          const float p = exp2f((sfr[nt][r] - mst[r]) * 1.44269504f);
          rsum[r] += p;
          Pbuf[wave][(quad * 4 + r) * 136 + nt * 16 + l16] = f2bf(p);
        }
      }
#pragma unroll
      for (int off = 1; off < 16; off <<= 1)
#pragma unroll
        for (int r = 0; r < 4; r++) rsum[r] += __shfl_xor(rsum[r], off, 64);
#pragma unroll
      for (int r = 0; r < 4; r++) lst[r] = lst[r] * alpha[r] + rsum[r];
#pragma unroll
      for (int ont = 0; ont < 4; ont++)
#pragma unroll
        for (int r = 0; r < 4; r++) oacc[ont][r] *= alpha[r];

      // wave-local RAW on Pbuf: DS ops complete in order per wave
      asm volatile("s_waitcnt lgkmcnt(0)" ::: "memory");

      bf16x8 ap[4];
#pragma unroll
      for (int c = 0; c < 4; c++)
        ap[c] = ld_frag(&Pbuf[wave][l16 * 136 + c * 32 + quad * 8]);
#pragma unroll
      for (int ont = 0; ont < 4; ont++) {
#pragma unroll
        for (int c = 0; c < 4; c++) {
          bf16x8 bv = ld_frag(&Vt[(ont * 16 + l16) * 136 + c * 32 + quad * 8]);
          oacc[ont] = __builtin_amdgcn_mfma_f32_16x16x32_bf16(ap[c], bv, oacc[ont], 0, 0, 0);
        }
      }
    }

    // epilogue: O / l -> attn_out ws [B][T][C] bf16
#pragma unroll
    for (int ont = 0; ont < 4; ont++) {
#pragma unroll
      for (int r = 0; r < 4; r++) {
        const float val = oacc[ont][r] / lst[r];
        const int row = row_g + r;
        o[((long)(b * T_SEQ + row)) * DM + h * DH + ont * 16 + l16] = f2bf(val);
      }
    }
  }
}

// ---------------------------------------------------------------------------
extern "C" void kernel_launch(void* const* d_in, const int* in_sizes, int n_in,
                              void* d_out, int out_size, void* d_ws, size_t ws_size,
                              hipStream_t stream) {
  const float* x      = (const float*)d_in[0];
  const float* qkv_w  = (const float*)d_in[1];
  const float* qkv_b  = (const float*)d_in[2];
  const float* proj_w = (const float*)d_in[3];
  const float* proj_b = (const float*)d_in[4];
  float* out = (float*)d_out;

  u16* ws = (u16*)d_ws;
  const long per = (long)NB * NH * T_SEQ * DH;  // 4,194,304 elems
  u16* q_ws = ws;
  u16* k_ws = ws + per;
  u16* v_ws = ws + 2 * per;              // transposed [B][H][DH][T]
  u16* ao_ws = ws + 3 * per;             // aliases x_bf (x dead after gemm0)
  u16* x_bf  = ws + 3 * per;
  u16* w_bf  = ws + 4 * per;             // qkv_w_bf during gemm0, proj_w_bf after
  // peak ws: 4*per + 3*DM*DM elems = 39.85 MB

  dim3 blk(256);
  cvt_f32_bf16<<<2048, blk, 0, stream>>>(x, x_bf, (int)(per / 8));
  cvt_f32_bf16<<<1536, blk, 0, stream>>>(qkv_w, w_bf, 3 * DM * DM / 8);
  gemm_nt<0><<<dim3(24, 32), blk, 0, stream>>>(x_bf, w_bf, qkv_b, nullptr,
                                               q_ws, k_ws, v_ws, 4096, 3072, 1024);
  rope_kernel<<<8192, blk, 0, stream>>>(q_ws, k_ws);
  attn_kernel<<<dim3(16, 32), blk, 0, stream>>>(q_ws, k_ws, v_ws, ao_ws);
  cvt_f32_bf16<<<512, blk, 0, stream>>>(proj_w, w_bf, DM * DM / 8);
  gemm_nt<1><<<dim3(8, 32), blk, 0, stream>>>(ao_ws, w_bf, proj_b, out,
                                              nullptr, nullptr, nullptr, 4096, 1024, 1024);
}